// Round 3
// baseline (166.186 us; speedup 1.0000x reference)
//
#include <hip/hip_runtime.h>
#include <math.h>

// Problem constants
#define N_IMG 16
#define C_CH 3
#define H_DIM 512
#define W_DIM 512
#define HW (H_DIM * W_DIM)              // 262144
#define KS 7
#define PAD 3

// Tiling: one 64x64 output region per block (1024 blocks, 4 blocks/CU, all
// co-resident). LDS holds the full 70-row x 72-col residual tile; it is
// staged in two chunks (rows 0..37, rows 38..69) so chunk1's global loads
// can be issued into registers BEFORE computing outputs 0..31 (T14 async
// stage split: load latency hides under the compute phase).
#define TSX 64
#define TROWS 70
#define TSTRIDE 72                      // LDS row stride (floats)
#define TPB 256
#define GPR 18                          // float4 groups per row (72 cols)
#define NG0 (38 * GPR)                  // 684 groups, rows 0..37
#define NG1 (32 * GPR)                  // 576 groups, rows 38..69
#define TILES_PER_IMG 64
#define NBLOCKS (N_IMG * TILES_PER_IMG) // 1024

// ws layout: pr/pr2/pc [NBLOCKS] per-block partials (no atomics anywhere)

__device__ __forceinline__ int reflect_y(int gy) {
    return (gy < 0) ? -gy : ((gy >= H_DIM) ? (2 * H_DIM - 2 - gy) : gy);
}
__device__ __forceinline__ int reflect_x(int gx) {
    return (gx < 0) ? -gx : ((gx >= W_DIM) ? (2 * W_DIM - 2 - gx) : gx);
}

struct Raw6 { float4 a0, a1, a2, b0, b1, b2; };

// Issue the 6 global loads (pred/targ x 3 ch) for one float4-group.
__device__ __forceinline__ void issue_group(const float* __restrict__ p0,
                                            const float* __restrict__ p1,
                                            const float* __restrict__ p2,
                                            const float* __restrict__ q0,
                                            const float* __restrict__ q1,
                                            const float* __restrict__ q2,
                                            int y0log, int xa, int r, int g,
                                            Raw6& o) {
    const int gy  = reflect_y(y0log + r);
    const int gx0 = xa + 4 * g;
    if (gx0 >= 0 && gx0 <= (W_DIM - 4)) {
        const int off = gy * W_DIM + gx0;           // 16B-aligned
        o.a0 = *(const float4*)(p0 + off);
        o.a1 = *(const float4*)(p1 + off);
        o.a2 = *(const float4*)(p2 + off);
        o.b0 = *(const float4*)(q0 + off);
        o.b1 = *(const float4*)(q1 + off);
        o.b2 = *(const float4*)(q2 + off);
    } else {                                         // x-border: scalar reflect
        int off[4];
#pragma unroll
        for (int j = 0; j < 4; ++j) off[j] = gy * W_DIM + reflect_x(gx0 + j);
        o.a0 = make_float4(p0[off[0]], p0[off[1]], p0[off[2]], p0[off[3]]);
        o.a1 = make_float4(p1[off[0]], p1[off[1]], p1[off[2]], p1[off[3]]);
        o.a2 = make_float4(p2[off[0]], p2[off[1]], p2[off[2]], p2[off[3]]);
        o.b0 = make_float4(q0[off[0]], q0[off[1]], q0[off[2]], q0[off[3]]);
        o.b1 = make_float4(q1[off[0]], q1[off[1]], q1[off[2]], q1[off[3]]);
        o.b2 = make_float4(q2[off[0]], q2[off[1]], q2[off[2]], q2[off[3]]);
    }
}

__device__ __forceinline__ void write_group(float* tile, int r, int g,
                                            const Raw6& o) {
    float4 res;
    res.x = fabsf(o.b0.x - o.a0.x) + fabsf(o.b1.x - o.a1.x) + fabsf(o.b2.x - o.a2.x);
    res.y = fabsf(o.b0.y - o.a0.y) + fabsf(o.b1.y - o.a1.y) + fabsf(o.b2.y - o.a2.y);
    res.z = fabsf(o.b0.z - o.a0.z) + fabsf(o.b1.z - o.a1.z) + fabsf(o.b2.z - o.a2.z);
    res.w = fabsf(o.b0.w - o.a0.w) + fabsf(o.b1.w - o.a1.w) + fabsf(o.b2.w - o.a2.w);
    *(float4*)&tile[r * TSTRIDE + g * 4] = res;
}

// 7x7 sliding-window variance over 8 vertically-adjacent outputs at (ty0, tx).
__device__ __forceinline__ void win_accum(const float* tile, int tx, int ty0,
                                          float& acc_r, float& acc_r2,
                                          float& acc_c) {
    float rS[KS], rSS[KS];
    float S = 0.f, SS = 0.f;
#pragma unroll
    for (int dy = 0; dy < KS; ++dy) {
        float s = 0.f, ss = 0.f;
#pragma unroll
        for (int j = 0; j < KS; ++j) {
            const float v = tile[(ty0 + dy) * TSTRIDE + tx + 1 + j];
            s  += v;
            ss += v * v;
        }
        rS[dy] = s; rSS[dy] = ss;
        S += s; SS += ss;
    }
#pragma unroll
    for (int k = 0; k < 8; ++k) {
        if (k > 0) {
            float s = 0.f, ss = 0.f;
#pragma unroll
            for (int j = 0; j < KS; ++j) {
                const float v = tile[(ty0 + 6 + k) * TSTRIDE + tx + 1 + j];
                s  += v;
                ss += v * v;
            }
            const int slot = k - 1;      // compile-time after unroll
            S  += s  - rS[slot];
            SS += ss - rSS[slot];
            rS[slot] = s; rSS[slot] = ss;
        }
        const float pix_var = (SS - S * S * (1.0f / 49.0f)) * (1.0f / 48.0f);
        const float center  = tile[(ty0 + 3 + k) * TSTRIDE + tx + 4];
        acc_r  += center;
        acc_r2 += center * center;
        acc_c  += pix_var * center;
    }
}

__global__ __launch_bounds__(TPB, 4) void k_fused(const float* __restrict__ pred,
                                                  const float* __restrict__ targ,
                                                  float* __restrict__ pr,
                                                  float* __restrict__ pr2,
                                                  float* __restrict__ pc) {
    __shared__ float tile[TROWS * TSTRIDE];

    // Bijective XCD swizzle (1024 % 8 == 0): XCD x owns contiguous works
    // [x*128, x*128+127] = 2 whole images -> halo re-reads are L2-local.
    const int wg  = ((blockIdx.x & 7) << 7) | (blockIdx.x >> 3);
    const int n   = wg >> 6;               // 64 tiles per image
    const int t   = wg & 63;
    const int by  = t >> 3;                // 8 tile-rows
    const int bx  = t & 7;                 // 8 tile-cols
    const int tid = threadIdx.x;

    const float* p0 = pred + (size_t)n * C_CH * HW;
    const float* p1 = p0 + HW;
    const float* p2 = p1 + HW;
    const float* q0 = targ + (size_t)n * C_CH * HW;
    const float* q1 = q0 + HW;
    const float* q2 = q1 + HW;

    const int y0log = by * TSX - PAD;      // gy of LDS row 0
    const int xa    = bx * TSX - 4;        // gx of LDS col 0 (16B-aligned)

    // --- chunk 0: rows 0..37 (684 groups), classic load->residual->write ---
#pragma unroll
    for (int s = 0; s < 3; ++s) {
        const int gi = tid + s * TPB;
        if (gi < NG0) {
            const int r = (unsigned)gi / GPR;
            const int g = (unsigned)gi % GPR;
            Raw6 o;
            issue_group(p0, p1, p2, q0, q1, q2, y0log, xa, r, g, o);
            write_group(tile, r, g, o);
        }
    }
    __syncthreads();                        // tile rows 0..37 visible

    // --- issue chunk 1 loads (rows 38..69, 576 groups) into registers ---
    // Sets A,B cover all 256 threads; set C is wave 0 only (64 groups).
    Raw6 A, B, Cg;
    {
        const int giA = tid;                // 0..255
        issue_group(p0, p1, p2, q0, q1, q2, y0log, xa,
                    38 + (unsigned)giA / GPR, (unsigned)giA % GPR, A);
        const int giB = tid + TPB;          // 256..511
        issue_group(p0, p1, p2, q0, q1, q2, y0log, xa,
                    38 + (unsigned)giB / GPR, (unsigned)giB % GPR, B);
    }
    __builtin_amdgcn_sched_barrier(0);      // pin loads above the compute phase

    // --- compute outputs 0..31 (reads rows 0..37) while loads fly ---
    const int tx  = tid & 63;
    const int ty0 = (tid >> 6) << 3;        // 0,8,16,24
    float acc_r = 0.f, acc_r2 = 0.f, acc_c = 0.f;
    win_accum(tile, tx, ty0, acc_r, acc_r2, acc_c);

    // --- set C issue (wave 0 only, wave-uniform branch), then writes ---
    const bool hasC = (tid < 64);
    if (hasC) {
        const int giC = tid + 2 * TPB;      // 512..575
        issue_group(p0, p1, p2, q0, q1, q2, y0log, xa,
                    38 + (unsigned)giC / GPR, (unsigned)giC % GPR, Cg);
    }
    {
        const int giA = tid;
        write_group(tile, 38 + (unsigned)giA / GPR, (unsigned)giA % GPR, A);
        const int giB = tid + TPB;
        write_group(tile, 38 + (unsigned)giB / GPR, (unsigned)giB % GPR, B);
        if (hasC) {
            const int giC = tid + 2 * TPB;
            write_group(tile, 38 + (unsigned)giC / GPR, (unsigned)giC % GPR, Cg);
        }
    }
    __syncthreads();                        // tile rows 38..69 visible

    // --- compute outputs 32..63 (reads rows 32..69, 6-row halo shared) ---
    win_accum(tile, tx, 32 + ty0, acc_r, acc_r2, acc_c);

    // --- block reduce 3 floats (wave shuffle -> LDS -> thread 0) ---
#pragma unroll
    for (int off = 32; off > 0; off >>= 1) {
        acc_r  += __shfl_down(acc_r,  off);
        acc_r2 += __shfl_down(acc_r2, off);
        acc_c  += __shfl_down(acc_c,  off);
    }
    __shared__ float sh_r[4], sh_r2[4], sh_c[4];
    const int lane = tid & 63;
    const int wave = tid >> 6;
    if (lane == 0) { sh_r[wave] = acc_r; sh_r2[wave] = acc_r2; sh_c[wave] = acc_c; }
    __syncthreads();
    if (tid == 0) {
        pr [wg] = sh_r [0] + sh_r [1] + sh_r [2] + sh_r [3];
        pr2[wg] = sh_r2[0] + sh_r2[1] + sh_r2[2] + sh_r2[3];
        pc [wg] = sh_c [0] + sh_c [1] + sh_c [2] + sh_c [3];
    }
}

// ---------------------------------------------------------------------------
// Finalize: wave w reduces image w's 64 partials in double; lane 0 applies
// pw_n = pvar^0.2; thread 0 sums the 16 images and writes the scalar.
// ---------------------------------------------------------------------------
__global__ void k_final(const float* __restrict__ pr,
                        const float* __restrict__ pr2,
                        const float* __restrict__ pc,
                        float* __restrict__ out) {
    __shared__ double sh[N_IMG];
    const int tid  = threadIdx.x;       // 1024 threads = 16 waves
    const int w    = tid >> 6;          // image index
    const int lane = tid & 63;

    const int idx = w * TILES_PER_IMG + lane;
    double R  = (double)pr [idx];
    double R2 = (double)pr2[idx];
    double Cs = (double)pc [idx];
#pragma unroll
    for (int off = 32; off > 0; off >>= 1) {
        R  += __shfl_down(R,  off);
        R2 += __shfl_down(R2, off);
        Cs += __shfl_down(Cs, off);
    }
    if (lane == 0) {
        const double pvar = (R2 - R * R / (double)HW) / (double)(HW - 1);
        sh[w] = pow(pvar, 0.2) * Cs;
    }
    __syncthreads();
    if (tid == 0) {
        double s = 0.0;
        for (int i = 0; i < N_IMG; ++i) s += sh[i];
        out[0] = (float)(s / ((double)N_IMG * C_CH * HW));
    }
}

extern "C" void kernel_launch(void* const* d_in, const int* in_sizes, int n_in,
                              void* d_out, int out_size, void* d_ws, size_t ws_size,
                              hipStream_t stream) {
    const float* pred = (const float*)d_in[0];
    const float* targ = (const float*)d_in[1];

    float* pr  = (float*)d_ws;
    float* pr2 = pr  + NBLOCKS;
    float* pc  = pr2 + NBLOCKS;
    float* out = (float*)d_out;

    k_fused<<<NBLOCKS, TPB, 0, stream>>>(pred, targ, pr, pr2, pc);
    k_final<<<1, 1024, 0, stream>>>(pr, pr2, pc, out);
}

// Round 4
// 137.698 us; speedup vs baseline: 1.2069x; 1.2069x over previous
//
#include <hip/hip_runtime.h>
#include <math.h>

// Problem constants
#define N_IMG 16
#define C_CH 3
#define H_DIM 512
#define W_DIM 512
#define HW (H_DIM * W_DIM)              // 262144
#define KS 7
#define PAD 3

// Wave-private slab design: each block owns a 64x64 output tile; each of its
// 4 waves owns a 64-wide x 16-tall output slab and stages its own 22-row x
// 72-col residual halo into a PRIVATE LDS region. Stage->compute handoff is
// wave-synchronous (s_waitcnt lgkmcnt(0)), NO __syncthreads between stage and
// compute -> the 16 waves/CU free-run and self-stagger, overlapping one
// wave's global loads with another's LDS/VALU compute (fixes the
// stage/compute convoy that phase-locked rounds 0-2).
#define TSX 64
#define SLABROWS 22                     // 16 outputs + 6 halo rows
#define TSTRIDE 72                      // LDS row stride (floats), 16B-aligned cols
#define SLABFLTS (SLABROWS * TSTRIDE)   // 1584 floats per wave slab
#define TPB 256
#define GPR 18                          // float4 groups per row
#define NGRP (SLABROWS * GPR)           // 396 groups per slab
#define TILES_PER_IMG 64
#define NBLOCKS (N_IMG * TILES_PER_IMG) // 1024

// ws layout: pr/pr2/pc [NBLOCKS] per-block partials (no atomics anywhere)

__device__ __forceinline__ int reflect_y(int gy) {
    return (gy < 0) ? -gy : ((gy >= H_DIM) ? (2 * H_DIM - 2 - gy) : gy);
}
__device__ __forceinline__ int reflect_x(int gx) {
    return (gx < 0) ? -gx : ((gx >= W_DIM) ? (2 * W_DIM - 2 - gx) : gx);
}

__global__ __launch_bounds__(TPB) void k_fused(const float* __restrict__ pred,
                                               const float* __restrict__ targ,
                                               float* __restrict__ pr,
                                               float* __restrict__ pr2,
                                               float* __restrict__ pc) {
    __shared__ float tile[4 * SLABFLTS];    // 25344 B: 4 wave-private slabs

    // Bijective XCD swizzle (1024 % 8 == 0): XCD x owns 2 whole images ->
    // halo re-reads are L2-local.
    const int wg   = ((blockIdx.x & 7) << 7) | (blockIdx.x >> 3);
    const int n    = wg >> 6;              // 64 tiles per image
    const int t    = wg & 63;
    const int by   = t >> 3;               // 8 tile-rows
    const int bx   = t & 7;                // 8 tile-cols
    const int tid  = threadIdx.x;
    const int wave = tid >> 6;
    const int lane = tid & 63;

    float* wt = &tile[wave * SLABFLTS];    // this wave's private slab

    const float* p0 = pred + (size_t)n * C_CH * HW;
    const float* p1 = p0 + HW;
    const float* p2 = p1 + HW;
    const float* q0 = targ + (size_t)n * C_CH * HW;
    const float* q1 = q0 + HW;
    const float* q2 = q1 + HW;

    const int y0w = by * TSX + wave * 16 - PAD;   // gy of slab row 0
    const int xa  = bx * TSX - 4;                 // gx of slab col 0 (16B-aligned)

    // --- stage this wave's 22x72 residual slab (396 float4-groups, 64 lanes) ---
#pragma unroll
    for (int it = 0; it < 7; ++it) {
        const int gi = lane + it * 64;
        if (gi < NGRP) {
            const unsigned r = (unsigned)gi / GPR;
            const unsigned g = (unsigned)gi % GPR;
            const int gy  = reflect_y(y0w + (int)r);
            const int gx0 = xa + 4 * (int)g;
            float4 a0, a1, a2, b0, b1, b2;
            if (gx0 >= 0 && gx0 <= (W_DIM - 4)) {
                const int off = gy * W_DIM + gx0;           // 16B-aligned
                a0 = *(const float4*)(p0 + off);
                a1 = *(const float4*)(p1 + off);
                a2 = *(const float4*)(p2 + off);
                b0 = *(const float4*)(q0 + off);
                b1 = *(const float4*)(q1 + off);
                b2 = *(const float4*)(q2 + off);
            } else {                                        // x-border (bx 0/7 only)
                int off[4];
#pragma unroll
                for (int j = 0; j < 4; ++j) off[j] = gy * W_DIM + reflect_x(gx0 + j);
                a0 = make_float4(p0[off[0]], p0[off[1]], p0[off[2]], p0[off[3]]);
                a1 = make_float4(p1[off[0]], p1[off[1]], p1[off[2]], p1[off[3]]);
                a2 = make_float4(p2[off[0]], p2[off[1]], p2[off[2]], p2[off[3]]);
                b0 = make_float4(q0[off[0]], q0[off[1]], q0[off[2]], q0[off[3]]);
                b1 = make_float4(q1[off[0]], q1[off[1]], q1[off[2]], q1[off[3]]);
                b2 = make_float4(q2[off[0]], q2[off[1]], q2[off[2]], q2[off[3]]);
            }
            float4 res;
            res.x = fabsf(b0.x - a0.x) + fabsf(b1.x - a1.x) + fabsf(b2.x - a2.x);
            res.y = fabsf(b0.y - a0.y) + fabsf(b1.y - a1.y) + fabsf(b2.y - a2.y);
            res.z = fabsf(b0.z - a0.z) + fabsf(b1.z - a1.z) + fabsf(b2.z - a2.z);
            res.w = fabsf(b0.w - a0.w) + fabsf(b1.w - a1.w) + fabsf(b2.w - a2.w);
            *(float4*)&wt[r * TSTRIDE + g * 4] = res;
        }
    }

    // Wave-synchronous handoff: slab is wave-private, so only this wave's
    // outstanding DS ops must complete (no __syncthreads -> no block convoy).
    asm volatile("s_waitcnt lgkmcnt(0)" ::: "memory");

    // --- 16 outputs per lane (slab column tx): 7x7 sliding-window variance ---
    // output col tx -> slab cols tx+1..tx+7 (center tx+4); output row k ->
    // window slab rows k..k+6, center slab row k+3.
    const int tx = lane;
    float rS[KS], rSS[KS];
    float S = 0.f, SS = 0.f;
#pragma unroll
    for (int dy = 0; dy < KS; ++dy) {
        float s = 0.f, ss = 0.f;
#pragma unroll
        for (int j = 0; j < KS; ++j) {
            const float v = wt[dy * TSTRIDE + tx + 1 + j];
            s  += v;
            ss += v * v;
        }
        rS[dy] = s; rSS[dy] = ss;
        S += s; SS += ss;
    }

    float acc_r = 0.f, acc_r2 = 0.f, acc_c = 0.f;
#pragma unroll
    for (int k = 0; k < 16; ++k) {
        if (k > 0) {
            float s = 0.f, ss = 0.f;
#pragma unroll
            for (int j = 0; j < KS; ++j) {
                const float v = wt[(6 + k) * TSTRIDE + tx + 1 + j];
                s  += v;
                ss += v * v;
            }
            const int slot = (k - 1) % KS;   // compile-time after unroll
            S  += s  - rS[slot];
            SS += ss - rSS[slot];
            rS[slot] = s; rSS[slot] = ss;
        }
        const float pix_var = (SS - S * S * (1.0f / 49.0f)) * (1.0f / 48.0f);
        const float center  = wt[(3 + k) * TSTRIDE + tx + 4];
        acc_r  += center;
        acc_r2 += center * center;
        acc_c  += pix_var * center;
    }

    // --- block reduce 3 floats (wave shuffle -> LDS -> thread 0) ---
#pragma unroll
    for (int off = 32; off > 0; off >>= 1) {
        acc_r  += __shfl_down(acc_r,  off);
        acc_r2 += __shfl_down(acc_r2, off);
        acc_c  += __shfl_down(acc_c,  off);
    }
    __shared__ float sh_r[4], sh_r2[4], sh_c[4];
    if (lane == 0) { sh_r[wave] = acc_r; sh_r2[wave] = acc_r2; sh_c[wave] = acc_c; }
    __syncthreads();                       // only barrier in the kernel (tail)
    if (tid == 0) {
        pr [wg] = sh_r [0] + sh_r [1] + sh_r [2] + sh_r [3];
        pr2[wg] = sh_r2[0] + sh_r2[1] + sh_r2[2] + sh_r2[3];
        pc [wg] = sh_c [0] + sh_c [1] + sh_c [2] + sh_c [3];
    }
}

// ---------------------------------------------------------------------------
// Finalize: wave w reduces image w's 64 partials in double; lane 0 applies
// pw_n = pvar^0.2; thread 0 sums the 16 images and writes the scalar.
// ---------------------------------------------------------------------------
__global__ void k_final(const float* __restrict__ pr,
                        const float* __restrict__ pr2,
                        const float* __restrict__ pc,
                        float* __restrict__ out) {
    __shared__ double sh[N_IMG];
    const int tid  = threadIdx.x;       // 1024 threads = 16 waves
    const int w    = tid >> 6;          // image index
    const int lane = tid & 63;

    const int idx = w * TILES_PER_IMG + lane;
    double R  = (double)pr [idx];
    double R2 = (double)pr2[idx];
    double Cs = (double)pc [idx];
#pragma unroll
    for (int off = 32; off > 0; off >>= 1) {
        R  += __shfl_down(R,  off);
        R2 += __shfl_down(R2, off);
        Cs += __shfl_down(Cs, off);
    }
    if (lane == 0) {
        const double pvar = (R2 - R * R / (double)HW) / (double)(HW - 1);
        sh[w] = pow(pvar, 0.2) * Cs;
    }
    __syncthreads();
    if (tid == 0) {
        double s = 0.0;
        for (int i = 0; i < N_IMG; ++i) s += sh[i];
        out[0] = (float)(s / ((double)N_IMG * C_CH * HW));
    }
}

extern "C" void kernel_launch(void* const* d_in, const int* in_sizes, int n_in,
                              void* d_out, int out_size, void* d_ws, size_t ws_size,
                              hipStream_t stream) {
    const float* pred = (const float*)d_in[0];
    const float* targ = (const float*)d_in[1];

    float* pr  = (float*)d_ws;
    float* pr2 = pr  + NBLOCKS;
    float* pc  = pr2 + NBLOCKS;
    float* out = (float*)d_out;

    k_fused<<<NBLOCKS, TPB, 0, stream>>>(pred, targ, pr, pr2, pc);
    k_final<<<1, 1024, 0, stream>>>(pr, pr2, pc, out);
}

// Round 7
// 133.735 us; speedup vs baseline: 1.2426x; 1.0296x over previous
//
#include <hip/hip_runtime.h>
#include <math.h>

// Problem constants
#define N_IMG 16
#define C_CH 3
#define H_DIM 512
#define W_DIM 512
#define HW (H_DIM * W_DIM)              // 262144
#define KS 7

// Streaming design: each WAVE owns a 64-col x 32-row output strip and walks
// it top-to-bottom, one output row per iteration. No staging phase, no
// __syncthreads: 6 scalar loads per lane per row are issued every iteration
// (consumed the NEXT iteration), so global loads are continuously in flight
// (~12 KB/CU at 8 waves/CU) while VALU + LDS window work proceeds. Vertical
// 7-window via per-lane 8-deep residual ring (all indices compile-time via
// the unroll-by-8 macro calls); horizontal 7-window via a wave-private LDS
// row of (colS, colSS) float2 entries (70 used) read with 7 ds_read_b64 taps.
// Lane l covers residual column x0-3+l; lanes 0..5 also cover dual columns
// x0+61..x0+66, so all 70 halo'd columns are produced by the wave itself.
// Reflect-x/-y are folded into load addresses: zero special cases anywhere.
//
// RACE FIX (round 6 -> 7): the cs[] write -> neighbor-tap read is cross-lane
// communication through LDS with NO intervening sync. Per-thread alias
// analysis sees distinct addresses and may hoist the taps above the writes.
// An asm "memory" fence + s_waitcnt lgkmcnt(0) + sched_barrier(0) between
// write and taps pins program order and guarantees the write committed.
#define SPANW 64                        // output cols per wave
#define RSTRIP 32                       // output rows per wave
#define WAVES_PER_IMG 128               // 8 spans * 16 v-strips
#define NSTRIPS (N_IMG * WAVES_PER_IMG) // 2048
#define TPB 256
#define NBLK (NSTRIPS / 4)              // 512 blocks (4 waves each)

__device__ __forceinline__ int reflect_y(int y) {
    return (y < 0) ? -y : ((y >= H_DIM) ? (2 * H_DIM - 2 - y) : y);
}
__device__ __forceinline__ int reflect_x(int x) {
    return (x < 0) ? -x : ((x >= W_DIM) ? (2 * W_DIM - 2 - x) : x);
}

// One output row RR (ring phase RI, literal 0..7 so all ring indices are
// compile-time): issue row RR+4 loads into NXT, consume CUR (raw row RR+3)
// into the ring + running column sums, LDS-exchange (colS,colSS), 7-tap
// horizontal window, accumulate the three partials.
#define STEP(RR, RI, CUR, NXT, CURD, NXTD)                                    \
  {                                                                           \
    const int gy_ = reflect_y((RR) + 4);                                      \
    const int on_ = gy_ * W_DIM + colp;                                       \
    NXT[0] = p0[on_]; NXT[1] = p1[on_]; NXT[2] = p2[on_];                     \
    NXT[3] = q0[on_]; NXT[4] = q1[on_]; NXT[5] = q2[on_];                     \
    if (dual) {                                                               \
      const int od_ = gy_ * W_DIM + cold;                                     \
      NXTD[0] = p0[od_]; NXTD[1] = p1[od_]; NXTD[2] = p2[od_];                \
      NXTD[3] = q0[od_]; NXTD[4] = q1[od_]; NXTD[5] = q2[od_];                \
    }                                                                         \
    const float vn_ = fabsf(CUR[3] - CUR[0]) + fabsf(CUR[4] - CUR[1])         \
                    + fabsf(CUR[5] - CUR[2]);                                 \
    const float vo_ = v1r[((RI) + 4) & 7];     /* row RR-4 */                 \
    S1 += vn_ - vo_; SS1 += vn_ * vn_ - vo_ * vo_;                            \
    v1r[((RI) + 3) & 7] = vn_;                 /* row RR+3 in, RR-5 out */    \
    if (dual) {                                                               \
      const float wn_ = fabsf(CURD[3] - CURD[0]) + fabsf(CURD[4] - CURD[1])   \
                      + fabsf(CURD[5] - CURD[2]);                             \
      const float wo_ = v2r[((RI) + 4) & 7];                                  \
      S2 += wn_ - wo_; SS2 += wn_ * wn_ - wo_ * wo_;                          \
      v2r[((RI) + 3) & 7] = wn_;                                              \
    }                                                                         \
    cs[wave][lane] = make_float2(S1, SS1);                                    \
    if (dual) cs[wave][64 + lane] = make_float2(S2, SS2);                     \
    asm volatile("s_waitcnt lgkmcnt(0)" ::: "memory");                        \
    __builtin_amdgcn_sched_barrier(0);                                        \
    float wS_ = 0.f, wSS_ = 0.f;                                              \
    _Pragma("unroll")                                                         \
    for (int j_ = 0; j_ < 7; ++j_) {                                          \
      const float2 t_ = cs[wave][lane + j_];                                  \
      wS_ += t_.x; wSS_ += t_.y;                                              \
    }                                                                         \
    const float c1_ = __shfl(v1r[(RI) & 7], (lane + 3) & 63);                 \
    const float c2_ = __shfl(v2r[(RI) & 7], (lane - 61) & 63);                \
    const float ctr_ = (lane < 61) ? c1_ : c2_;                               \
    const float pv_ = (wSS_ - wS_ * wS_ * (1.0f / 49.0f)) * (1.0f / 48.0f);   \
    acc_r += ctr_; acc_r2 += ctr_ * ctr_; acc_c += pv_ * ctr_;                \
  }

__global__ __launch_bounds__(TPB) void k_fused(const float* __restrict__ pred,
                                               const float* __restrict__ targ,
                                               float* __restrict__ pr,
                                               float* __restrict__ pr2,
                                               float* __restrict__ pc) {
    __shared__ float2 cs[4][72];            // wave-private colS/colSS rows

    // Bijective XCD swizzle (512 % 8 == 0): XCD x gets a contiguous 64-block
    // chunk = 2 whole images -> halo/row re-reads are L2-local.
    const int wg   = ((blockIdx.x & 7) << 6) | (blockIdx.x >> 3);
    const int tid  = threadIdx.x;
    const int wave = tid >> 6;              // uniform within the wave
    const int lane = tid & 63;
    const int sid  = wg * 4 + wave;         // strip id, wave-uniform
    const int img  = sid >> 7;              // 128 strips per image
    const int rem  = sid & 127;
    const int x0   = (rem & 7) * SPANW;     // span
    const int r0   = (rem >> 3) * RSTRIP;   // v-strip (multiple of 8)

    const float* p0 = pred + (size_t)img * C_CH * HW;
    const float* p1 = p0 + HW;
    const float* p2 = p1 + HW;
    const float* q0 = targ + (size_t)img * C_CH * HW;
    const float* q1 = q0 + HW;
    const float* q2 = q1 + HW;

    const int  colp = reflect_x(x0 - 3 + lane);   // primary column
    const int  cold = reflect_x(x0 + 61 + lane);  // dual column (lanes 0..5)
    const bool dual = (lane < 6);

    float v1r[8] = {0, 0, 0, 0, 0, 0, 0, 0};
    float v2r[8] = {0, 0, 0, 0, 0, 0, 0, 0};
    float S1 = 0.f, SS1 = 0.f, S2 = 0.f, SS2 = 0.f;

    // --- prologue: ring rows r0-5 .. r0+2 into slots (r-r0)&7; S/SS over
    // rows r0-4..r0+2 (i=1..7) so iter r0's "+row r0+3 - row r0-4" lands
    // exactly on the reflect-padded window rows r0-3..r0+3.
#pragma unroll
    for (int i = 0; i < 8; ++i) {
        const int gy = reflect_y(r0 - 5 + i);
        const int o  = gy * W_DIM + colp;
        const float v = fabsf(q0[o] - p0[o]) + fabsf(q1[o] - p1[o])
                      + fabsf(q2[o] - p2[o]);
        v1r[(i + 3) & 7] = v;
        if (i != 0) { S1 += v; SS1 += v * v; }
        if (dual) {
            const int o2 = gy * W_DIM + cold;
            const float w = fabsf(q0[o2] - p0[o2]) + fabsf(q1[o2] - p1[o2])
                          + fabsf(q2[o2] - p2[o2]);
            v2r[(i + 3) & 7] = w;
            if (i != 0) { S2 += w; SS2 += w * w; }
        }
    }

    // --- preload raw row r0+3 (consumed by iteration r0) ---
    float ra[6], rb[6], da[6], db[6];
    {
        const int gy = reflect_y(r0 + 3);
        const int o  = gy * W_DIM + colp;
        ra[0] = p0[o]; ra[1] = p1[o]; ra[2] = p2[o];
        ra[3] = q0[o]; ra[4] = q1[o]; ra[5] = q2[o];
        if (dual) {
            const int o2 = gy * W_DIM + cold;
            da[0] = p0[o2]; da[1] = p1[o2]; da[2] = p2[o2];
            da[3] = q0[o2]; da[4] = q1[o2]; da[5] = q2[o2];
        }
    }

    float acc_r = 0.f, acc_r2 = 0.f, acc_c = 0.f;

    // --- main loop: 32 output rows, unrolled by 8 (ring slots static) ---
    for (int ro = 0; ro < RSTRIP / 8; ++ro) {
        const int rb8 = r0 + ro * 8;
        STEP(rb8 + 0, 0, ra, rb, da, db)
        STEP(rb8 + 1, 1, rb, ra, db, da)
        STEP(rb8 + 2, 2, ra, rb, da, db)
        STEP(rb8 + 3, 3, rb, ra, db, da)
        STEP(rb8 + 4, 4, ra, rb, da, db)
        STEP(rb8 + 5, 5, rb, ra, db, da)
        STEP(rb8 + 6, 6, ra, rb, da, db)
        STEP(rb8 + 7, 7, rb, ra, db, da)
    }

    // --- per-wave reduce 3 floats, one partial set per strip ---
#pragma unroll
    for (int off = 32; off > 0; off >>= 1) {
        acc_r  += __shfl_down(acc_r,  off);
        acc_r2 += __shfl_down(acc_r2, off);
        acc_c  += __shfl_down(acc_c,  off);
    }
    if (lane == 0) { pr[sid] = acc_r; pr2[sid] = acc_r2; pc[sid] = acc_c; }
}

// ---------------------------------------------------------------------------
// Finalize: wave w reduces image w's 128 partials in double; lane 0 applies
// pw_n = pvar^0.2; thread 0 sums the 16 images and writes the scalar.
// ---------------------------------------------------------------------------
__global__ void k_final(const float* __restrict__ pr,
                        const float* __restrict__ pr2,
                        const float* __restrict__ pc,
                        float* __restrict__ out) {
    __shared__ double sh[N_IMG];
    const int tid  = threadIdx.x;       // 1024 threads = 16 waves
    const int w    = tid >> 6;          // image index
    const int lane = tid & 63;

    const int i0 = w * WAVES_PER_IMG + lane;
    double R  = (double)pr [i0] + (double)pr [i0 + 64];
    double R2 = (double)pr2[i0] + (double)pr2[i0 + 64];
    double Cs = (double)pc [i0] + (double)pc [i0 + 64];
#pragma unroll
    for (int off = 32; off > 0; off >>= 1) {
        R  += __shfl_down(R,  off);
        R2 += __shfl_down(R2, off);
        Cs += __shfl_down(Cs, off);
    }
    if (lane == 0) {
        const double pvar = (R2 - R * R / (double)HW) / (double)(HW - 1);
        sh[w] = pow(pvar, 0.2) * Cs;
    }
    __syncthreads();
    if (tid == 0) {
        double s = 0.0;
        for (int i = 0; i < N_IMG; ++i) s += sh[i];
        out[0] = (float)(s / ((double)N_IMG * C_CH * HW));
    }
}

extern "C" void kernel_launch(void* const* d_in, const int* in_sizes, int n_in,
                              void* d_out, int out_size, void* d_ws, size_t ws_size,
                              hipStream_t stream) {
    const float* pred = (const float*)d_in[0];
    const float* targ = (const float*)d_in[1];

    float* pr  = (float*)d_ws;
    float* pr2 = pr  + NSTRIPS;
    float* pc  = pr2 + NSTRIPS;
    float* out = (float*)d_out;

    k_fused<<<NBLK, TPB, 0, stream>>>(pred, targ, pr, pr2, pc);
    k_final<<<1, 1024, 0, stream>>>(pr, pr2, pc, out);
}